// Round 6
// baseline (471.291 us; speedup 1.0000x reference)
//
#include <hip/hip_runtime.h>
#include <stdint.h>

#define N_TOK 4096
#define DIM   256
#define NH    4
#define DH    64
#define TOPK  30
#define CANDN 40      // candidate margin: approx-top-40 superset of exact top-30
#define ATT_SCALE 0.25f
#define LN_EPS 1e-5f

typedef __attribute__((ext_vector_type(8))) short bf16x8;  // 8 bf16 in 4 VGPRs
typedef __attribute__((ext_vector_type(4))) float f32x4;

static __device__ __forceinline__ ushort f2bf(float f) {   // RNE
    uint x = __float_as_uint(f);
    return (ushort)((x + 0x7FFFu + ((x >> 16) & 1u)) >> 16);
}
static __device__ __forceinline__ bf16x8 load_frag(const ushort* p) {
    union { int4 i; bf16x8 f; } u;
    u.i = *reinterpret_cast<const int4*>(p);
    return u.f;
}
static __device__ __forceinline__ uint s16key(uint u) {    // bf16 bits -> sortable u16
    return (u & 0x8000u) ? (u ^ 0xFFFFu) : (u | 0x8000u);
}

// ---------------------------------------------------------------------------
// Fused q+k fp32 GEMM NT (exactness needed for rescoring).
// ---------------------------------------------------------------------------
#define BK 32
__global__ __launch_bounds__(256) void qk_gemm_f32(
    const float* __restrict__ query_in, const float* __restrict__ key_in,
    const float* __restrict__ Wq, const float* __restrict__ bq,
    const float* __restrict__ Wk, const float* __restrict__ bk,
    float* __restrict__ qf, float* __restrict__ kf,
    ushort* __restrict__ qb, ushort* __restrict__ kb)
{
    const int j0g = blockIdx.x * 64;          // 0..511
    const int sel = j0g >> 8;                 // 0=q, 1=k
    const int j0  = j0g & 255;
    const float* A    = sel ? key_in : query_in;
    const float* W    = sel ? Wk : Wq;
    const float* bias = sel ? bk : bq;
    float*  outF = sel ? kf : qf;
    ushort* outB = sel ? kb : qb;

    __shared__ float As[BK][64 + 4];
    __shared__ float Ws[BK][64 + 4];
    const int tid = threadIdx.x;
    const int tx = tid & 15;
    const int ty = tid >> 4;
    const int i0 = blockIdx.y * 64;

    float acc[4][4];
#pragma unroll
    for (int r = 0; r < 4; r++)
#pragma unroll
        for (int c = 0; c < 4; c++) acc[r][c] = 0.f;

    for (int k0 = 0; k0 < DIM; k0 += BK) {
#pragma unroll
        for (int u = 0; u < 2; u++) {
            const int f = u * 256 + tid;
            const int r = f >> 3;
            const int c = (f & 7) * 4;
            float4 va = *reinterpret_cast<const float4*>(A + (size_t)(i0 + r) * DIM + k0 + c);
            As[c + 0][r] = va.x; As[c + 1][r] = va.y;
            As[c + 2][r] = va.z; As[c + 3][r] = va.w;
            float4 vw = *reinterpret_cast<const float4*>(W + (size_t)(j0 + r) * DIM + k0 + c);
            Ws[c + 0][r] = vw.x; Ws[c + 1][r] = vw.y;
            Ws[c + 2][r] = vw.z; Ws[c + 3][r] = vw.w;
        }
        __syncthreads();
#pragma unroll
        for (int kk = 0; kk < BK; kk++) {
            const float4 a4 = *reinterpret_cast<const float4*>(&As[kk][ty * 4]);
            const float4 b4 = *reinterpret_cast<const float4*>(&Ws[kk][tx * 4]);
            const float ar[4] = {a4.x, a4.y, a4.z, a4.w};
            const float br[4] = {b4.x, b4.y, b4.z, b4.w};
#pragma unroll
            for (int r = 0; r < 4; r++)
#pragma unroll
                for (int c = 0; c < 4; c++) acc[r][c] += ar[r] * br[c];
        }
        __syncthreads();
    }

#pragma unroll
    for (int r = 0; r < 4; r++) {
        const int gi = i0 + ty * 4 + r;
#pragma unroll
        for (int c = 0; c < 4; c++) {
            const int gj = j0 + tx * 4 + c;
            float v = acc[r][c] + bias[gj];
            outF[(size_t)gi * DIM + gj] = v;
            outB[(size_t)gi * DIM + gj] = f2bf(v);
        }
    }
}

// ---------------------------------------------------------------------------
// Cast fp32 -> bf16: value_in (1M), Wv (64K), Wo (64K).
// ---------------------------------------------------------------------------
__global__ __launch_bounds__(256) void cast_kernel(
    const float* __restrict__ value_in, const float* __restrict__ Wv,
    const float* __restrict__ Wo, ushort* __restrict__ value_b,
    ushort* __restrict__ Wv_b, ushort* __restrict__ Wo_b)
{
    const int id4 = blockIdx.x * 256 + threadIdx.x;   // one float4 per thread
    const int NV = 1048576 / 4, NW = 65536 / 4;
    const float* src; ushort* dst; int off;
    if (id4 < NV)            { src = value_in; dst = value_b; off = id4; }
    else if (id4 < NV + NW)  { src = Wv; dst = Wv_b; off = id4 - NV; }
    else                     { src = Wo; dst = Wo_b; off = id4 - NV - NW; }
    float4 v = reinterpret_cast<const float4*>(src)[off];
    ushort4 o = {f2bf(v.x), f2bf(v.y), f2bf(v.z), f2bf(v.w)};
    reinterpret_cast<ushort4*>(dst)[off] = o;
}

// ---------------------------------------------------------------------------
// bf16 MFMA GEMM NT (v-projection and out-projection).
// ---------------------------------------------------------------------------
__global__ __launch_bounds__(256) void mfma_gemm(
    const ushort* __restrict__ A, const ushort* __restrict__ B,
    const float* __restrict__ bias, const float* __restrict__ addX,
    float* __restrict__ outF)
{
    const int lane = threadIdx.x & 63;
    const int wv   = threadIdx.x >> 6;
    const int i0   = blockIdx.y * 64 + wv * 16;
    const int j0   = blockIdx.x * 64;
    const int r = lane & 15, q = lane >> 4;

    f32x4 acc[4];
#pragma unroll
    for (int b = 0; b < 4; b++) acc[b] = (f32x4){0.f, 0.f, 0.f, 0.f};

#pragma unroll
    for (int ks = 0; ks < 8; ks++) {
        const int kk = ks * 32 + q * 8;
        bf16x8 af = load_frag(A + (size_t)(i0 + r) * DIM + kk);
        bf16x8 bfr[4];
#pragma unroll
        for (int jt = 0; jt < 4; jt++)
            bfr[jt] = load_frag(B + (size_t)(j0 + jt * 16 + r) * DIM + kk);
#pragma unroll
        for (int jt = 0; jt < 4; jt++)
            acc[jt] = __builtin_amdgcn_mfma_f32_16x16x32_bf16(af, bfr[jt], acc[jt], 0, 0, 0);
    }

#pragma unroll
    for (int jt = 0; jt < 4; jt++) {
        const int gj = j0 + jt * 16 + r;          // col = lane&15
        const float bv = bias[gj];
#pragma unroll
        for (int rg = 0; rg < 4; rg++) {          // row = (lane>>4)*4+reg
            const int gi = i0 + q * 4 + rg;
            float v = acc[jt][rg] + bv;
            if (addX) v += addX[(size_t)gi * DIM + gj];
            outF[(size_t)gi * DIM + gj] = v;
        }
    }
}

// ---------------------------------------------------------------------------
// Approx scores -> sortable u16 keys. Epilogue now stages the 32x128 u16
// wave-tile in LDS (per-wave slice, no barrier: DS pipe is in-order per
// wave) and writes coalesced dwordx4 (round-5 wrote 64 scattered 2B stores
// per tile).
// ---------------------------------------------------------------------------
__global__ __launch_bounds__(256) void scores_kernel(
    const ushort* __restrict__ qb, const ushort* __restrict__ kb,
    ushort* __restrict__ sb)
{
    const int lane = threadIdx.x & 63;
    const int wv   = threadIdx.x >> 6;
    const int h    = blockIdx.z;
    const int i0   = blockIdx.y * 128 + wv * 32;
    const int j0   = blockIdx.x * 128;
    const int r = lane & 15, q = lane >> 4;
    const int koff = h * DH;

    __shared__ ushort st[4][32][136];   // 128 + 8 pad (16B-multiple row stride)

    f32x4 acc[2][8];
#pragma unroll
    for (int a = 0; a < 2; a++)
#pragma unroll
        for (int b = 0; b < 8; b++) acc[a][b] = (f32x4){0.f, 0.f, 0.f, 0.f};

#pragma unroll
    for (int ks = 0; ks < 2; ks++) {
        const int kk = koff + ks * 32 + q * 8;
        bf16x8 af[2], bfr[8];
#pragma unroll
        for (int mt = 0; mt < 2; mt++)
            af[mt] = load_frag(qb + (size_t)(i0 + mt * 16 + r) * DIM + kk);
#pragma unroll
        for (int jt = 0; jt < 8; jt++)
            bfr[jt] = load_frag(kb + (size_t)(j0 + jt * 16 + r) * DIM + kk);
#pragma unroll
        for (int mt = 0; mt < 2; mt++)
#pragma unroll
            for (int jt = 0; jt < 8; jt++)
                acc[mt][jt] = __builtin_amdgcn_mfma_f32_16x16x32_bf16(
                    af[mt], bfr[jt], acc[mt][jt], 0, 0, 0);
    }

    // stage tile in LDS (C layout: row=(lane>>4)*4+reg, col=lane&15)
#pragma unroll
    for (int mt = 0; mt < 2; mt++)
#pragma unroll
        for (int jt = 0; jt < 8; jt++)
#pragma unroll
            for (int rg = 0; rg < 4; rg++)
                st[wv][mt * 16 + q * 4 + rg][jt * 16 + r] =
                    (ushort)s16key(f2bf(acc[mt][jt][rg]));

    // coalesced write-out: 4 rows x 256B per iteration (same wave -> in order)
    const int rr = lane >> 4, seg = lane & 15;
#pragma unroll
    for (int it = 0; it < 8; it++) {
        const int rowl = it * 4 + rr;
        const int gi = i0 + rowl;
        int4 vdat = *reinterpret_cast<const int4*>(&st[wv][rowl][seg * 8]);
        *reinterpret_cast<int4*>(sb + ((size_t)(h * N_TOK + gi)) * N_TOK + j0 + seg * 8) = vdat;
    }
}

// ---------------------------------------------------------------------------
// Selection v4. 4 independent rows per 256-thr block, NO __syncthreads (all
// LDS structures are per-wave slices; the DS pipe executes one wave's ops in
// order, so same-wave RAW through LDS needs no barrier). If attnRow != null,
// the wave also writes its final fp32 attn row: 16 coalesced int4 zero
// stores issued early, compute overlaps the drain, s_waitcnt vmcnt(0), then
// <=30 scalar patch stores (distinct addresses).
// ---------------------------------------------------------------------------
__global__ __launch_bounds__(256) void select_kernel(
    const ushort* __restrict__ sb, const float* __restrict__ qf,
    const float* __restrict__ kf, const float* __restrict__ vf,
    float* __restrict__ pval, int* __restrict__ pidx,
    ushort* __restrict__ ctxb, float* __restrict__ attnRow)
{
    const int lane = threadIdx.x & 63;
    const int wv   = threadIdx.x >> 6;
    const int row  = blockIdx.x * 4 + wv;      // 0..16383
    const int h    = row >> 12;
    const int i    = row & (N_TOK - 1);
    const ushort* srow = sb + (size_t)row * N_TOK;

    __shared__ uint  hist[4][256];
    __shared__ uint  cand[4][64];
    __shared__ uint  ccnt[4];
    __shared__ float pw[4][TOPK];
    __shared__ int   jw[4][TOPK];
    __shared__ __align__(16) float qsh[4][DH];

    qsh[wv][lane] = qf[(size_t)i * DIM + h * DH + lane];
    if (lane == 0) ccnt[wv] = 0;
#pragma unroll
    for (int b = 0; b < 4; b++) hist[wv][b * 64 + lane] = 0u;  // stride-64: free

    uint kw[32];
    const int4* srow4 = reinterpret_cast<const int4*>(srow);
#pragma unroll
    for (int t = 0; t < 8; t++) {
        int4 c = srow4[t * 64 + lane];
        kw[t * 4 + 0] = (uint)c.x; kw[t * 4 + 1] = (uint)c.y;
        kw[t * 4 + 2] = (uint)c.z; kw[t * 4 + 3] = (uint)c.w;
    }

    uint mx = 0;
#pragma unroll
    for (int w = 0; w < 32; w++) {
        uint lo16 = kw[w] & 0xFFFFu, hi16 = kw[w] >> 16;
        mx = max(mx, max(lo16, hi16));
    }
#pragma unroll
    for (int off = 32; off; off >>= 1)
        mx = max(mx, (uint)__shfl_xor((int)mx, off));

#pragma unroll
    for (int w = 0; w < 32; w++) {
        uint d0 = mx - (kw[w] & 0xFFFFu);
        uint d1 = mx - (kw[w] >> 16);
        if (d0 < 255u) atomicAdd(&hist[wv][d0], 1u);
        if (d1 < 255u) atomicAdd(&hist[wv][d1], 1u);
    }

    const uint c0 = hist[wv][lane * 4 + 0];
    const uint c1 = hist[wv][lane * 4 + 1];
    const uint c2 = hist[wv][lane * 4 + 2];
    const uint c3 = hist[wv][lane * 4 + 3];
    const uint seg = c0 + c1 + c2 + c3;
    uint scan = seg;
#pragma unroll
    for (int d = 1; d < 64; d <<= 1) {
        uint y = (uint)__shfl_up((int)scan, d);
        if (lane >= d) scan += y;
    }
    const uint excl = scan - seg;
    const bool crossing = (excl < CANDN) && (scan >= CANDN);
    unsigned long long bal = __ballot(crossing);

    int t = 256;
    if (bal != 0ull) {
        const int srcLane = __ffsll(bal) - 1;
        int tloc = lane * 4;
        if (crossing) {
            uint cum = excl + c0;
            if (cum < CANDN) { tloc++; cum += c1;
                if (cum < CANDN) { tloc++; cum += c2;
                    if (cum < CANDN) { tloc++; } } }
        }
        t = __shfl(tloc, srcLane);
    }

    uint T;
    if (t <= 254) {
        T = mx - (uint)t;
    } else {
        uint lo = 0;
#pragma unroll
        for (int b = 15; b >= 0; b--) {
            uint trial = lo | (1u << b);
            int c = 0;
#pragma unroll
            for (int w = 0; w < 32; w++) {
                c += ((kw[w] & 0xFFFFu) >= trial) ? 1 : 0;
                c += ((kw[w] >> 16)     >= trial) ? 1 : 0;
            }
#pragma unroll
            for (int off = 32; off; off >>= 1) c += __shfl_xor(c, off);
            if (c >= CANDN) lo = trial;
        }
        T = lo;
    }

    // early coalesced zero of the final attn row (drains while we compute)
    if (attnRow) {
        float4* rowg = reinterpret_cast<float4*>(attnRow + (size_t)row * N_TOK);
        const float4 z = {0.f, 0.f, 0.f, 0.f};
#pragma unroll
        for (int tt = 0; tt < 16; tt++) rowg[tt * 64 + lane] = z;
    }

#pragma unroll
    for (int w = 0; w < 32; w++) {
        const uint lo16 = kw[w] & 0xFFFFu, hi16 = kw[w] >> 16;
        const int jbase = (w >> 2) * 512 + lane * 8 + (w & 3) * 2;
        if (lo16 >= T) {
            uint pos = atomicAdd(&ccnt[wv], 1u);
            if (pos < 64u) cand[wv][pos] = (uint)jbase;
        }
        if (hi16 >= T) {
            uint pos = atomicAdd(&ccnt[wv], 1u);
            if (pos < 64u) cand[wv][pos] = (uint)(jbase + 1);
        }
    }
    const int m = (int)min(ccnt[wv], 64u);

    unsigned long long ukey = 0ull;
    if (lane < m) {
        const int j = (int)cand[wv][lane];
        const float4* kr = reinterpret_cast<const float4*>(kf + (size_t)j * DIM + h * DH);
        const float4* qr = reinterpret_cast<const float4*>(qsh[wv]);
        float s = 0.f;
#pragma unroll
        for (int d = 0; d < 16; d++) {
            float4 a = qr[d], bb = kr[d];
            s += a.x * bb.x; s += a.y * bb.y; s += a.z * bb.z; s += a.w * bb.w;
        }
        uint bits = __float_as_uint(s);
        uint s32 = (bits & 0x80000000u) ? ~bits : (bits | 0x80000000u);
        ukey = ((unsigned long long)s32 << 12) | (unsigned long long)(4095 - j);
    }

#pragma unroll
    for (int k = 2; k <= 64; k <<= 1) {
#pragma unroll
        for (int jj = k >> 1; jj > 0; jj >>= 1) {
            unsigned long long o = __shfl_xor(ukey, jj);
            bool keepMax = ((lane & jj) != 0) ^ ((lane & k) != 0);
            ukey = keepMax ? (ukey > o ? ukey : o) : (ukey < o ? ukey : o);
        }
    }

    const int rank = 63 - lane;
    const int jsel = 4095 - (int)(ukey & 0xFFFull);
    uint s32b = (uint)(ukey >> 12);
    uint fb = (s32b & 0x80000000u) ? (s32b ^ 0x80000000u) : ~s32b;
    const float sc = __uint_as_float(fb);
    const float stop = __shfl(sc, 63);

    float e = (rank < TOPK) ? __expf((sc - stop) * ATT_SCALE) : 0.f;
    float esum = e;
#pragma unroll
    for (int off = 32; off; off >>= 1) esum += __shfl_xor(esum, off);
    const float p = e / esum;

    if (rank < TOPK) {
        pw[wv][rank] = p; jw[wv][rank] = jsel;
        if (pval) {
            pval[(size_t)row * 32 + rank] = p;
            pidx[(size_t)row * 32 + rank] = jsel;
        }
    }

    float a = 0.f;
#pragma unroll
    for (int c = 0; c < TOPK; c++)
        a += pw[wv][c] * vf[(size_t)jw[wv][c] * DIM + h * DH + lane];
    ctxb[(size_t)i * DIM + h * DH + lane] = f2bf(a);

    if (attnRow) {
        // zero stores (and everything else) fully drained, then patch
        asm volatile("s_waitcnt vmcnt(0)" ::: "memory");
        if (rank < TOPK)
            attnRow[(size_t)row * N_TOK + jsel] = p;
    }
}

// ---------------------------------------------------------------------------
// attn_write (FALLBACK path only): 4 rows per block, LDS-staged.
// ---------------------------------------------------------------------------
__global__ __launch_bounds__(256) void attn_write(
    const float* __restrict__ pval, const int* __restrict__ pidx,
    float* __restrict__ attnF)
{
    __shared__ __align__(16) float rb[4][N_TOK];
    const int tid = threadIdx.x;
    const int r0 = blockIdx.x * 4;

    float4* rb4 = reinterpret_cast<float4*>(&rb[0][0]);
    const float4 z = {0.f, 0.f, 0.f, 0.f};
#pragma unroll
    for (int t = 0; t < 16; t++) rb4[t * 256 + tid] = z;
    __syncthreads();
    if (tid < 4 * TOPK) {
        const int w = tid / TOPK, c = tid % TOPK;
        rb[w][pidx[(size_t)(r0 + w) * 32 + c]] = pval[(size_t)(r0 + w) * 32 + c];
    }
    __syncthreads();
#pragma unroll
    for (int w = 0; w < 4; w++) {
        float4* grow = reinterpret_cast<float4*>(attnF + (size_t)(r0 + w) * N_TOK);
#pragma unroll
        for (int t = 0; t < 4; t++)
            grow[t * 256 + tid] = rb4[w * 1024 + t * 256 + tid];
    }
}

// ---------------------------------------------------------------------------
// Row LayerNorm (biased var), in-place on fp32 resid. One wave per row.
// ---------------------------------------------------------------------------
__global__ __launch_bounds__(64) void ln_kernel(
    float* __restrict__ resb, const float* __restrict__ g,
    const float* __restrict__ b)
{
    const int i = blockIdx.x, lane = threadIdx.x;
    float4* rowp = reinterpret_cast<float4*>(resb + (size_t)i * DIM);
    float4 x = rowp[lane];
    float s  = x.x + x.y + x.z + x.w;
    float sq = x.x * x.x + x.y * x.y + x.z * x.z + x.w * x.w;
#pragma unroll
    for (int off = 32; off; off >>= 1) {
        s  += __shfl_xor(s, off);
        sq += __shfl_xor(sq, off);
    }
    const float mu  = s * (1.f / DIM);
    const float var = sq * (1.f / DIM) - mu * mu;
    const float rstd = rsqrtf(var + LN_EPS);
    const int col = lane * 4;
    float4 o;
    o.x = (x.x - mu) * rstd * g[col + 0] + b[col + 0];
    o.y = (x.y - mu) * rstd * g[col + 1] + b[col + 1];
    o.z = (x.z - mu) * rstd * g[col + 2] + b[col + 2];
    o.w = (x.w - mu) * rstd * g[col + 3] + b[col + 3];
    rowp[lane] = o;
}

// ---------------------------------------------------------------------------
extern "C" void kernel_launch(void* const* d_in, const int* in_sizes, int n_in,
                              void* d_out, int out_size, void* d_ws, size_t ws_size,
                              hipStream_t stream)
{
    const float* key_in   = (const float*)d_in[0];
    const float* value_in = (const float*)d_in[1];
    const float* query_in = (const float*)d_in[2];
    const float* Wq = (const float*)d_in[3];
    const float* bq = (const float*)d_in[4];
    const float* Wk = (const float*)d_in[5];
    const float* bk = (const float*)d_in[6];
    const float* Wv = (const float*)d_in[7];
    const float* bv = (const float*)d_in[8];
    const float* Wo = (const float*)d_in[9];
    const float* bo = (const float*)d_in[10];
    const float* ln_g = (const float*)d_in[11];
    const float* ln_b = (const float*)d_in[12];

    float* outF  = (float*)d_out;                     // (N, D) fp32
    float* attnF = outF + (size_t)N_TOK * DIM;        // (H, N, N) fp32

    const size_t KEYB = (size_t)NH * N_TOK * N_TOK * 2;      // 128 MB keys
    const size_t NEED = KEYB + (21u << 20);

    if (ws_size >= NEED) {
        // -------- primary path: all scratch in d_ws; select writes attnF ----
        char* ws = (char*)d_ws;
        ushort* sb      = (ushort*)ws;
        float*  qf      = (float*)(ws + KEYB);
        float*  kf      = (float*)(ws + KEYB + (4u  << 20));
        float*  vf      = (float*)(ws + KEYB + (8u  << 20));
        ushort* qb      = (ushort*)(ws + KEYB + (12u << 20));
        ushort* kb      = (ushort*)(ws + KEYB + (14u << 20));
        ushort* ctxb    = (ushort*)(ws + KEYB + (16u << 20));
        ushort* value_b = (ushort*)(ws + KEYB + (18u << 20));
        ushort* Wv_b    = (ushort*)(ws + KEYB + (20u << 20));
        ushort* Wo_b    = (ushort*)(ws + KEYB + (20u << 20) + 131072);

        cast_kernel<<<dim3((1048576 + 65536 + 65536) / 4 / 256), 256, 0, stream>>>(
            value_in, Wv, Wo, value_b, Wv_b, Wo_b);
        qk_gemm_f32<<<dim3(8, 64), 256, 0, stream>>>(
            query_in, key_in, Wq, bq, Wk, bk, qf, kf, qb, kb);
        mfma_gemm<<<dim3(4, 64), 256, 0, stream>>>(value_b, Wv_b, bv, nullptr, vf);

        scores_kernel<<<dim3(32, 32, NH), 256, 0, stream>>>(qb, kb, sb);
        select_kernel<<<dim3(N_TOK * NH / 4), 256, 0, stream>>>(
            sb, qf, kf, vf, nullptr, nullptr, ctxb, attnF);

        mfma_gemm<<<dim3(4, 64), 256, 0, stream>>>(ctxb, Wo_b, bo, query_in, outF);
        ln_kernel<<<N_TOK, 64, 0, stream>>>(outF, ln_g, ln_b);
    } else {
        // -------- fallback (round-5 structure): scratch inside attnF --------
        const size_t SC = 33554432;
        ushort* sb   = (ushort*)attnF;
        float*  qf   = attnF + SC;
        float*  kf   = attnF + SC + 1048576;
        float*  vf   = attnF + SC + 2097152;
        ushort* qb   = (ushort*)(attnF + SC + 3145728);
        ushort* kb   = (ushort*)(attnF + SC + 3670016);
        ushort* ctxb = (ushort*)(attnF + SC + 4194304);

        float*  pval    = (float*)d_ws;
        int*    pidx    = (int*)d_ws + 524288;
        ushort* value_b = (ushort*)((char*)d_ws + (4u << 20));
        ushort* Wv_b    = (ushort*)((char*)d_ws + (6u << 20));
        ushort* Wo_b    = (ushort*)((char*)d_ws + (6u << 20) + 131072);

        cast_kernel<<<dim3((1048576 + 65536 + 65536) / 4 / 256), 256, 0, stream>>>(
            value_in, Wv, Wo, value_b, Wv_b, Wo_b);
        qk_gemm_f32<<<dim3(8, 64), 256, 0, stream>>>(
            query_in, key_in, Wq, bq, Wk, bk, qf, kf, qb, kb);
        mfma_gemm<<<dim3(4, 64), 256, 0, stream>>>(value_b, Wv_b, bv, nullptr, vf);

        scores_kernel<<<dim3(32, 32, NH), 256, 0, stream>>>(qb, kb, sb);
        select_kernel<<<dim3(N_TOK * NH / 4), 256, 0, stream>>>(
            sb, qf, kf, vf, pval, pidx, ctxb, nullptr);

        mfma_gemm<<<dim3(4, 64), 256, 0, stream>>>(ctxb, Wo_b, bo, query_in, outF);
        ln_kernel<<<N_TOK, 64, 0, stream>>>(outF, ln_g, ln_b);

        attn_write<<<N_TOK * NH / 4, 256, 0, stream>>>(pval, pidx, attnF);
    }
}